// Round 5
// baseline (112.898 us; speedup 1.0000x reference)
//
#include <hip/hip_runtime.h>
#include <hip/hip_bf16.h>

#define ALPHA 0.2f
#define NEG_BIG -1e12f

constexpr int B_ = 8, N_ = 2048, C_ = 128;
constexpr int JB = 128, NJT = N_ / JB;   // 16 j-tiles of 128

typedef __attribute__((ext_vector_type(8))) short short8;
typedef __attribute__((ext_vector_type(8))) unsigned short ushort8;
typedef __attribute__((ext_vector_type(4))) float f32x4;

__device__ __forceinline__ unsigned short f2bf(float f) {
    unsigned int u = __float_as_uint(f);
    u += 0x7fffu + ((u >> 16) & 1u);
    return (unsigned short)(u >> 16);
}

__device__ __forceinline__ unsigned int cvtpk_bf16(float lo, float hi) {
    unsigned int r;
    asm("v_cvt_pk_bf16_f32 %0, %1, %2" : "=v"(r) : "v"(lo), "v"(hi));
    return r;
}

// ---------------------------------------------------------------------------
// Kernel 1: hidden = x @ W (f32, exact), emit hiddenT bf16 [B, C, N] and
// attn1/attn2 = hidden @ a (f32, exact).  64 rows per block, 256 threads.
// ---------------------------------------------------------------------------
__global__ __launch_bounds__(256) void k1_hidden(
    const float* __restrict__ x, const float* __restrict__ W,
    const float* __restrict__ a, unsigned short* __restrict__ hT,
    float* __restrict__ at1, float* __restrict__ at2)
{
    __shared__ float xs[64][C_];   // 32 KB
    __shared__ float Ws[C_][C_];   // 64 KB
    const int tid = threadIdx.x;
    const int row0 = blockIdx.x * 64;   // global row = b*N + n

    {
        const float4* xsrc = (const float4*)(x + (size_t)row0 * C_);
        float4* xdst = (float4*)&xs[0][0];
        for (int i = tid; i < 64 * C_ / 4; i += 256) xdst[i] = xsrc[i];
        const float4* wsrc = (const float4*)W;
        float4* wdst = (float4*)&Ws[0][0];
        for (int i = tid; i < C_ * C_ / 4; i += 256) wdst[i] = wsrc[i];
    }
    __syncthreads();

    const int tr = tid >> 5, tc = tid & 31;
    const int r0 = tr * 8, c0 = tc * 4;

    float acc[8][4];
#pragma unroll
    for (int i = 0; i < 8; ++i)
#pragma unroll
        for (int j = 0; j < 4; ++j) acc[i][j] = 0.f;

    for (int k = 0; k < C_; k += 4) {
        float4 w0 = *(const float4*)&Ws[k + 0][c0];
        float4 w1 = *(const float4*)&Ws[k + 1][c0];
        float4 w2 = *(const float4*)&Ws[k + 2][c0];
        float4 w3 = *(const float4*)&Ws[k + 3][c0];
#pragma unroll
        for (int rr = 0; rr < 8; ++rr) {
            float4 xv = *(const float4*)&xs[r0 + rr][k];
            acc[rr][0] += xv.x * w0.x + xv.y * w1.x + xv.z * w2.x + xv.w * w3.x;
            acc[rr][1] += xv.x * w0.y + xv.y * w1.y + xv.z * w2.y + xv.w * w3.y;
            acc[rr][2] += xv.x * w0.z + xv.y * w1.z + xv.z * w2.z + xv.w * w3.z;
            acc[rr][3] += xv.x * w0.w + xv.y * w1.w + xv.z * w2.w + xv.w * w3.w;
        }
    }

    float av0[4], av1[4];
#pragma unroll
    for (int cc = 0; cc < 4; ++cc) {
        av0[cc] = a[(c0 + cc) * 2 + 0];
        av1[cc] = a[(c0 + cc) * 2 + 1];
    }
#pragma unroll
    for (int rr = 0; rr < 8; ++rr) {
        float s1 = acc[rr][0] * av0[0] + acc[rr][1] * av0[1] +
                   acc[rr][2] * av0[2] + acc[rr][3] * av0[3];
        float s2 = acc[rr][0] * av1[0] + acc[rr][1] * av1[1] +
                   acc[rr][2] * av1[2] + acc[rr][3] * av1[3];
#pragma unroll
        for (int off = 1; off < 32; off <<= 1) {
            s1 += __shfl_xor(s1, off);
            s2 += __shfl_xor(s2, off);
        }
        if (tc == 0) {
            at1[row0 + r0 + rr] = s1;
            at2[row0 + r0 + rr] = s2;
        }
    }

    const int b = row0 >> 11;
    const int n0 = row0 & (N_ - 1);
#pragma unroll
    for (int cc = 0; cc < 4; ++cc) {
        ushort8 hv;
#pragma unroll
        for (int rr = 0; rr < 8; ++rr) hv[rr] = f2bf(acc[rr][cc]);
        *(ushort8*)(hT + ((size_t)b * C_ + c0 + cc) * N_ + n0 + r0) = hv;
    }
}

// ---------------------------------------------------------------------------
// Kernel 2: barrier-free per-wave flash attention over the graph mask.
// Block = 128 threads = 2 independent waves; both handle the same 16 i-rows,
// each owns a 64-col c-half.  Swapped MFMA (A=hT, B=P) makes the softmax
// fully lane-local: lane (r=lane&15, jc=lane>>4) computes P[r][j] for
// j = jt*128 + ks*32 + jc*8 + e, which IS the B-fragment layout.  C/D:
// col = lane&15 = i-row, row = jc*4+reg = c_local.  No LDS state, no
// barriers in the loop, row-reduce = 2 shuffles.
// ---------------------------------------------------------------------------
__global__ __launch_bounds__(128, 2) void k2_attn(
    const int* __restrict__ adj, const unsigned short* __restrict__ hT,
    const float* __restrict__ at1, const float* __restrict__ at2,
    const float* __restrict__ bias, float* __restrict__ out)
{
    __shared__ float at2s[N_];                    // 8 KB
    const int tid = threadIdx.x;
    const int b  = blockIdx.x >> 7;               // 128 i-groups per batch
    const int i0 = (blockIdx.x & 127) * 16;

    {
        const float4* src = (const float4*)(at2 + (size_t)b * N_);
        float4* dst = (float4*)at2s;
#pragma unroll
        for (int k = 0; k < 4; ++k) dst[tid + 128 * k] = src[tid + 128 * k];
    }

    const int lane = tid & 63;
    const int wv = tid >> 6;                      // c-half 0/1
    const int r  = lane & 15;                     // softmax row (= C/D col)
    const int jc = lane >> 4;                     // 0..3

    const float a1v = at1[(size_t)b * N_ + i0 + r];
    const int* arow = adj + ((size_t)(b * N_ + i0 + r)) * N_ + jc * 8;
    // A-fragment rows: c = wv*64 + cb*16 + r
    const unsigned short* hrow = hT + ((size_t)b * C_ + wv * 64 + r) * N_ + jc * 8;

    f32x4 acc[4];
#pragma unroll
    for (int cb = 0; cb < 4; ++cb) acc[cb] = (f32x4){0.f, 0.f, 0.f, 0.f};
    float m = -3e38f, l = 0.f;

    // adj prefetch for jt=0: A[q], q = ks*2+h  ->  j = ks*32 + jc*8 + h*4 + (0..3)
    int4 A[8];
#pragma unroll
    for (int q = 0; q < 8; ++q)
        A[q] = *(const int4*)(arow + (q >> 1) * 32 + (q & 1) * 4);

    __syncthreads();   // at2s visible (once; no barriers in the loop below)

    for (int jt = 0; jt < NJT; ++jt) {
        // prefetch next adj tile (stays in flight across the whole iteration)
        const int jn = (jt + 1 < NJT ? jt + 1 : jt) * JB;
        int4 An[8];
#pragma unroll
        for (int q = 0; q < 8; ++q)
            An[q] = *(const int4*)(arow + jn + (q >> 1) * 32 + (q & 1) * 4);

        // hT A-fragments, cb 0..1 (issued early; softmax chain covers L2 latency)
        short8 h0[4], h1[4];
#pragma unroll
        for (int ks = 0; ks < 4; ++ks) {
            h0[ks] = *(const short8*)(hrow + jt * JB + ks * 32);
            h1[ks] = *(const short8*)(hrow + (size_t)16 * N_ + jt * JB + ks * 32);
        }

        // at2 for this tile from LDS
        float4 F[8];
#pragma unroll
        for (int q = 0; q < 8; ++q)
            F[q] = *(const float4*)&at2s[jt * JB + (q >> 1) * 32 + jc * 8 + (q & 1) * 4];

        // logits: p[ks*8 + e], e = h*4 + 0..3
        float p[32];
#pragma unroll
        for (int q = 0; q < 8; ++q) {
            float t;
            t = a1v + F[q].x; t = fmaxf(t, ALPHA * t); p[q * 4 + 0] = A[q].x > 0 ? t : NEG_BIG;
            t = a1v + F[q].y; t = fmaxf(t, ALPHA * t); p[q * 4 + 1] = A[q].y > 0 ? t : NEG_BIG;
            t = a1v + F[q].z; t = fmaxf(t, ALPHA * t); p[q * 4 + 2] = A[q].z > 0 ? t : NEG_BIG;
            t = a1v + F[q].w; t = fmaxf(t, ALPHA * t); p[q * 4 + 3] = A[q].w > 0 ? t : NEG_BIG;
        }

        // hT A-fragments, cb 2..3 (issued mid; exp/reduce covers them)
        short8 h2[4], h3[4];
#pragma unroll
        for (int ks = 0; ks < 4; ++ks) {
            h2[ks] = *(const short8*)(hrow + (size_t)32 * N_ + jt * JB + ks * 32);
            h3[ks] = *(const short8*)(hrow + (size_t)48 * N_ + jt * JB + ks * 32);
        }

        // row max: 5-level tree in-lane, then 2 shuffles across jc copies
        float u[16];
#pragma unroll
        for (int q = 0; q < 16; ++q) u[q] = fmaxf(p[q], p[q + 16]);
#pragma unroll
        for (int q = 0; q < 8; ++q) u[q] = fmaxf(u[q], u[q + 8]);
#pragma unroll
        for (int q = 0; q < 4; ++q) u[q] = fmaxf(u[q], u[q + 4]);
        float tm = fmaxf(fmaxf(u[0], u[1]), fmaxf(u[2], u[3]));
        tm = fmaxf(tm, __shfl_xor(tm, 16));
        tm = fmaxf(tm, __shfl_xor(tm, 32));

        const float m_new = fmaxf(m, tm);
        const float sc = __expf(m - m_new);
        m = m_new;

#pragma unroll
        for (int q = 0; q < 32; ++q) p[q] = __expf(p[q] - m_new);

        float v[16];
#pragma unroll
        for (int q = 0; q < 16; ++q) v[q] = p[q] + p[q + 16];
#pragma unroll
        for (int q = 0; q < 8; ++q) v[q] = v[q] + v[q + 8];
#pragma unroll
        for (int q = 0; q < 4; ++q) v[q] = v[q] + v[q + 4];
        float ps = (v[0] + v[1]) + (v[2] + v[3]);
        ps += __shfl_xor(ps, 16);
        ps += __shfl_xor(ps, 32);
        l = l * sc + ps;

        // pack P -> B-fragments (bf16)
        short8 Pb[4];
#pragma unroll
        for (int ks = 0; ks < 4; ++ks) {
            int4 w;
            w.x = (int)cvtpk_bf16(p[ks * 8 + 0], p[ks * 8 + 1]);
            w.y = (int)cvtpk_bf16(p[ks * 8 + 2], p[ks * 8 + 3]);
            w.z = (int)cvtpk_bf16(p[ks * 8 + 4], p[ks * 8 + 5]);
            w.w = (int)cvtpk_bf16(p[ks * 8 + 6], p[ks * 8 + 7]);
            Pb[ks] = *(short8*)&w;
        }

        // rescale + MFMA (8 independent acc chains of depth 4 across 4 cb)
#pragma unroll
        for (int cb = 0; cb < 4; ++cb) {
            acc[cb][0] *= sc; acc[cb][1] *= sc; acc[cb][2] *= sc; acc[cb][3] *= sc;
        }
        __builtin_amdgcn_s_setprio(1);
#pragma unroll
        for (int ks = 0; ks < 4; ++ks) {
            acc[0] = __builtin_amdgcn_mfma_f32_16x16x32_bf16(h0[ks], Pb[ks], acc[0], 0, 0, 0);
            acc[1] = __builtin_amdgcn_mfma_f32_16x16x32_bf16(h1[ks], Pb[ks], acc[1], 0, 0, 0);
            acc[2] = __builtin_amdgcn_mfma_f32_16x16x32_bf16(h2[ks], Pb[ks], acc[2], 0, 0, 0);
            acc[3] = __builtin_amdgcn_mfma_f32_16x16x32_bf16(h3[ks], Pb[ks], acc[3], 0, 0, 0);
        }
        __builtin_amdgcn_s_setprio(0);

#pragma unroll
        for (int q = 0; q < 8; ++q) A[q] = An[q];
    }

    // ---- epilogue: out[b][i0+r][wv*64 + cb*16 + jc*4 + reg] ----
    const float invl = 1.f / l;
#pragma unroll
    for (int cb = 0; cb < 4; ++cb) {
        const int c0 = wv * 64 + cb * 16 + jc * 4;
        float4 bv = *(const float4*)&bias[c0];
        float4 o;
        o.x = acc[cb][0] * invl + bv.x;
        o.y = acc[cb][1] * invl + bv.y;
        o.z = acc[cb][2] * invl + bv.z;
        o.w = acc[cb][3] * invl + bv.w;
        *(float4*)(out + ((size_t)(b * N_ + i0 + r)) * C_ + c0) = o;
    }
}

extern "C" void kernel_launch(void* const* d_in, const int* in_sizes, int n_in,
                              void* d_out, int out_size, void* d_ws, size_t ws_size,
                              hipStream_t stream) {
    const float* x    = (const float*)d_in[0];
    const int*   adj  = (const int*)d_in[1];
    const float* W    = (const float*)d_in[2];
    const float* a    = (const float*)d_in[3];
    const float* bias = (const float*)d_in[4];
    float* out = (float*)d_out;

    char* ws = (char*)d_ws;
    unsigned short* hT = (unsigned short*)ws;                        // 4 MB bf16 [B,C,N]
    float* at1 = (float*)(ws + (size_t)4 * 1024 * 1024);             // 64 KB
    float* at2 = (float*)(ws + (size_t)4 * 1024 * 1024 + 64 * 1024); // 64 KB

    k1_hidden<<<(B_ * N_) / 64, 256, 0, stream>>>(x, W, a, hT, at1, at2);
    k2_attn<<<B_ * (N_ / 16), 128, 0, stream>>>(adj, hT, at1, at2, bias, out);
}